// Round 1
// baseline (228.221 us; speedup 1.0000x reference)
//
#include <hip/hip_runtime.h>

// SIAF forward: B=131072 samples, D=64 dims, L=63 per-dim MLPs (fan-in l+1, HID=8, out 2).
// Strategy (round 0, fp32-exact):
//  - prep kernel: transpose/mask W1 [L,HID,L] -> w1t [64][64][8] (zero-padded; mask d<=l
//    is materialized as zeros), pad b1/W2/b2 to l=63 dummy row. All in d_ws (~135 KB).
//  - main kernel: 1 sample/thread, 128 thr/block. x row staged in LDS xl[d][t]
//    (column-private per thread -> no barriers, no bank conflicts: bank=(4d+t)%32... t varies).
//    Weights are wave-uniform -> compiler emits s_load (scalar pipe), keeping the
//    VALU free for the 32-FMA inner body (4 l-values blocked per x-read).
//  - z written in-place into xl (descending l-groups make overwrite safe), then one
//    coalesced-per-lane float4 store phase. log_det accumulated in a register.

#define DIMS 64
#define LNUM 63
#define HIDN 8
#define TPB  128
#define STR  128   // xl row stride (floats); accesses are lane-indexed -> conflict-free

// ws layout in floats
#define W1T_OFF 0                 // [64][64][8]
#define B1T_OFF (64*64*8)         // [64][8]
#define W2T_OFF (B1T_OFF + 64*8)  // [64][2][8]
#define B2T_OFF (W2T_OFF + 64*16) // [64][2]
#define WS_FLOATS (B2T_OFF + 64*2)

__global__ void siaf_prep(const float* __restrict__ W1, const float* __restrict__ b1,
                          const float* __restrict__ W2, const float* __restrict__ b2,
                          float* __restrict__ ws) {
    int i = blockIdx.x * blockDim.x + threadIdx.x;
    if (i < 64 * 64 * 8) {
        int h = i & 7, d = (i >> 3) & 63, l = i >> 9;
        float v = 0.0f;
        if (l < LNUM && d <= l) v = W1[(l * HIDN + h) * LNUM + d];
        ws[W1T_OFF + i] = v;
    } else if (i < B1T_OFF + 64 * 8) {
        int k = i - B1T_OFF;
        int h = k & 7, l = k >> 3;
        ws[i] = (l < LNUM) ? b1[l * HIDN + h] : 0.0f;
    } else if (i < W2T_OFF + 64 * 16) {
        int k = i - W2T_OFF;
        int oh = k & 15, l = k >> 4;
        ws[i] = (l < LNUM) ? W2[l * 16 + oh] : 0.0f;
    } else if (i < WS_FLOATS) {
        int k = i - B2T_OFF;
        int o = k & 1, l = k >> 1;
        ws[i] = (l < LNUM) ? b2[l * 2 + o] : 0.0f;
    }
}

__device__ __forceinline__ float fast_tanh(float a) {
    // tanh(a) = 1 - 2/(exp(2a)+1); saturates correctly at +-1 for large |a|
    float e = __expf(2.0f * a);
    return 1.0f - __fdividef(2.0f, e + 1.0f);
}

__global__ __launch_bounds__(TPB) void siaf_main(
        const float* __restrict__ x, const float* __restrict__ ip,
        const float* __restrict__ ws, float* __restrict__ out, int nB) {
    __shared__ float xl[DIMS * STR];
    const float* __restrict__ w1t = ws + W1T_OFF;
    const float* __restrict__ b1t = ws + B1T_OFF;
    const float* __restrict__ w2t = ws + W2T_OFF;
    const float* __restrict__ b2t = ws + B2T_OFF;

    const int t = threadIdx.x;
    const int sample = blockIdx.x * TPB + t;

    // stage this thread's x row into its private LDS column (16B-aligned float4 loads)
    const float4* __restrict__ xrow = (const float4*)(x + (size_t)sample * DIMS);
    #pragma unroll
    for (int i = 0; i < 16; ++i) {
        float4 v = xrow[i];
        xl[(4 * i + 0) * STR + t] = v.x;
        xl[(4 * i + 1) * STR + t] = v.y;
        xl[(4 * i + 2) * STR + t] = v.z;
        xl[(4 * i + 3) * STR + t] = v.w;
    }

    const float ip0 = ip[0], ip1 = ip[1];
    float lsum = ip1;  // log_det includes alpha[:,0] = initial_param[1]

    // process l in groups of 4, descending so z can overwrite x in-place:
    // group g writes xl rows 4g+1..4g+4; remaining groups read rows <= 4g-1.
    for (int g = 15; g >= 0; --g) {
        const int l0 = 4 * g;
        float acc[4][HIDN];
        #pragma unroll
        for (int j = 0; j < 4; ++j)
            #pragma unroll
            for (int h = 0; h < HIDN; ++h)
                acc[j][h] = b1t[(l0 + j) * HIDN + h];

        // shared K-range: d < l0 valid for all four l values. Weights are uniform
        // (s_load, scalar pipe); 1 ds_read_b32 of x feeds 32 FMAs.
        for (int d = 0; d < l0; ++d) {
            float xd = xl[d * STR + t];
            #pragma unroll
            for (int j = 0; j < 4; ++j)
                #pragma unroll
                for (int h = 0; h < HIDN; ++h)
                    acc[j][h] = fmaf(w1t[((l0 + j) * 64 + d) * HIDN + h], xd, acc[j][h]);
        }
        // ragged tail: l = l0+j additionally needs d = l0..l0+j
        #pragma unroll
        for (int jd = 0; jd < 4; ++jd) {
            int d = l0 + jd;
            float xd = xl[d * STR + t];
            #pragma unroll
            for (int j = 0; j < 4; ++j)
                if (jd <= j)
                    #pragma unroll
                    for (int h = 0; h < HIDN; ++h)
                        acc[j][h] = fmaf(w1t[((l0 + j) * 64 + d) * HIDN + h], xd, acc[j][h]);
        }

        // layer 2 + activation + z for dims l0+1..l0+4 (computed fully before overwrite)
        float zv[4];
        #pragma unroll
        for (int j = 0; j < 4; ++j) {
            const int l = l0 + j;
            float th[HIDN];
            #pragma unroll
            for (int h = 0; h < HIDN; ++h) th[h] = fast_tanh(acc[j][h]);
            float mu = b2t[l * 2 + 0], al = b2t[l * 2 + 1];
            #pragma unroll
            for (int h = 0; h < HIDN; ++h) {
                mu = fmaf(w2t[(l * 2 + 0) * HIDN + h], th[h], mu);
                al = fmaf(w2t[(l * 2 + 1) * HIDN + h], th[h], al);
            }
            if (l < LNUM) {
                lsum += al;
                zv[j] = xl[(l + 1) * STR + t] * __expf(al) + mu;
            } else {
                zv[j] = 0.0f;  // dummy padded layer l=63
            }
        }
        #pragma unroll
        for (int j = 0; j < 4; ++j)
            if (l0 + j < LNUM) xl[(l0 + j + 1) * STR + t] = zv[j];
    }

    // dim 0: z0 = x0 * exp(ip1) + ip0 (x row 0 never overwritten above)
    xl[t] = xl[t] * __expf(ip1) + ip0;

    // coalesced-per-lane float4 store of z
    float4* __restrict__ zrow = (float4*)(out + (size_t)sample * DIMS);
    #pragma unroll
    for (int i = 0; i < 16; ++i) {
        float4 v;
        v.x = xl[(4 * i + 0) * STR + t];
        v.y = xl[(4 * i + 1) * STR + t];
        v.z = xl[(4 * i + 2) * STR + t];
        v.w = xl[(4 * i + 3) * STR + t];
        zrow[i] = v;
    }
    out[(size_t)nB * DIMS + sample] = lsum;
}

extern "C" void kernel_launch(void* const* d_in, const int* in_sizes, int n_in,
                              void* d_out, int out_size, void* d_ws, size_t ws_size,
                              hipStream_t stream) {
    const float* x  = (const float*)d_in[0];
    const float* ip = (const float*)d_in[1];
    const float* W1 = (const float*)d_in[2];
    const float* b1 = (const float*)d_in[3];
    const float* W2 = (const float*)d_in[4];
    const float* b2 = (const float*)d_in[5];
    float* ws  = (float*)d_ws;
    float* out = (float*)d_out;

    const int nB = in_sizes[0] / DIMS;  // 131072

    siaf_prep<<<(WS_FLOATS + 255) / 256, 256, 0, stream>>>(W1, b1, W2, b2, ws);
    siaf_main<<<nB / TPB, TPB, 0, stream>>>(x, ip, ws, out, nB);
}

// Round 2
// 156.674 us; speedup vs baseline: 1.4567x; 1.4567x over previous
//
#include <hip/hip_runtime.h>

// SIAF forward via two fused transposed MFMA GEMMs (bf16 in, fp32 acc).
//   GEMM1: y[n=512][s] = sum_k w1b[n][k] * x[s][k]   (k=64; k==63 is the bias column, x_k=1)
//   h = tanh(y) -> bf16 -> wave-private LDS (64 k-rows rotating window)
//   GEMM2: out2[r=128][s] = sum_kl w2full[r][kl] * h[64*mt+kl][s]  (block-diag W2)
// C-layout of GEMM2 gives each lane complete (mu,alpha) pairs for 2 l-values ->
// z = x*exp(alpha)+mu and log_det computed in-lane, no cross-lane reductions
// (except the final 2-stage log_det sum over the 4 quads of a sample).
//
// Layouts used (m89/m118-verified, cdna_hip_programming.md §3):
//   A-frag: lane holds A[m=lane&15][k=quad*8+j], j = vector elem
//   B-frag: lane holds B[k=quad*8+j][n=lane&15]
//   C/D:    col=lane&15, row=quad*4+reg

#define DIMS 64

typedef __attribute__((ext_vector_type(8))) short short8;
typedef __attribute__((ext_vector_type(4))) float f32x4;
typedef unsigned short ushort_t;
typedef unsigned int uint_t;

__device__ __forceinline__ ushort_t f2bf(float f) {
    uint_t u = __float_as_uint(f);
    u += 0x7FFFu + ((u >> 16) & 1u);   // RNE; data has no NaN/Inf
    return (ushort_t)(u >> 16);
}

// ws layout: w1b ushort[512][64] | w2full ushort[128][64] | b2f float[128]
__global__ void siaf_prep(const float* __restrict__ W1, const float* __restrict__ b1,
                          const float* __restrict__ W2, const float* __restrict__ b2,
                          ushort_t* __restrict__ ws_u) {
    ushort_t* w1b    = ws_u;
    ushort_t* w2full = ws_u + 512 * 64;
    float*    b2f    = (float*)(ws_u + 512 * 64 + 128 * 64);
    int i = blockIdx.x * 256 + threadIdx.x;
    if (i < 512 * 64) {
        int k = i & 63, n = i >> 6, l = n >> 3, h = n & 7;
        float v = 0.0f;
        if (l < 63) {
            if (k < 63 && k <= l) v = W1[(l * 8 + h) * 63 + k];
            else if (k == 63)     v = b1[l * 8 + h];
        }
        w1b[i] = f2bf(v);
    } else if (i < 512 * 64 + 128 * 64) {
        int j = i - 512 * 64;
        int kl = j & 63, r = j >> 6, l = r >> 1, o = r & 1;
        float v = 0.0f;
        if (l < 63 && (kl >> 3) == (l & 7)) v = W2[(l * 2 + o) * 8 + (kl & 7)];
        w2full[j] = f2bf(v);
    } else if (i < 512 * 64 + 128 * 64 + 128) {
        int j = i - (512 * 64 + 128 * 64);
        int l = j >> 1, o = j & 1;
        b2f[j] = (l < 63) ? b2[l * 2 + o] : 0.0f;
    }
}

__device__ __forceinline__ float tanh_fast(float y) {
    float e = __expf(2.0f * y);
    return 1.0f - __fdividef(2.0f, e + 1.0f);
}

__global__ __launch_bounds__(256) void siaf_mfma(
        const float* __restrict__ x, const float* __restrict__ ip,
        const ushort_t* __restrict__ ws_u, float* __restrict__ out, int nB) {
    const ushort_t* w1b    = ws_u;
    const ushort_t* w2full = ws_u + 512 * 64;
    const float*    b2f    = (const float*)(ws_u + 512 * 64 + 128 * 64);

    // [wave][stile][sample16][36 dwords]: 64 bf16 k-rows + pad (stride 36dw -> 2-way max)
    __shared__ uint_t hbuf[4][2][16][36];

    const int tid  = threadIdx.x;
    const int wv   = tid >> 6, lane = tid & 63;
    const int s16  = lane & 15, quad = lane >> 4;
    const int sbase = blockIdx.x * 128 + wv * 32;

    const float ip0 = ip[0], ip1 = ip[1];

    // B-frags: x rows (2 sample-tiles x 2 k-halves), fp32 -> bf16, bias elem k=63 := 1.0
    short8 bfr[2][2];
    float  lsum[2];
    #pragma unroll
    for (int st = 0; st < 2; ++st) {
        const int s = sbase + st * 16 + s16;
        const float4* xp = (const float4*)(x + (size_t)s * DIMS);
        #pragma unroll
        for (int kh = 0; kh < 2; ++kh) {
            float4 va = xp[kh * 8 + quad * 2];
            float4 vb = xp[kh * 8 + quad * 2 + 1];
            float f[8] = {va.x, va.y, va.z, va.w, vb.x, vb.y, vb.z, vb.w};
            if (kh == 1 && quad == 3) f[7] = 1.0f;   // bias column
            short8 t;
            #pragma unroll
            for (int j = 0; j < 8; ++j) t[j] = (short)f2bf(f[j]);
            bfr[st][kh] = t;
        }
        lsum[st] = 0.0f;
    }

    for (int mt = 0; mt < 8; ++mt) {
        // ---- GEMM1: 4 tiles of 16 weight-rows -> h k-rows 64*mt .. 64*mt+63 ----
        #pragma unroll
        for (int t4 = 0; t4 < 4; ++t4) {
            const int tl = mt * 4 + t4;
            const ushort_t* w1p = w1b + (tl * 16 + s16) * 64;
            short8 a0 = *(const short8*)(w1p + quad * 8);
            short8 a1 = *(const short8*)(w1p + 32 + quad * 8);
            #pragma unroll
            for (int st = 0; st < 2; ++st) {
                f32x4 acc = {0.f, 0.f, 0.f, 0.f};
                acc = __builtin_amdgcn_mfma_f32_16x16x32_bf16(a0, bfr[st][0], acc, 0, 0, 0);
                acc = __builtin_amdgcn_mfma_f32_16x16x32_bf16(a1, bfr[st][1], acc, 0, 0, 0);
                float t0 = tanh_fast(acc[0]), t1 = tanh_fast(acc[1]);
                float t2 = tanh_fast(acc[2]), t3 = tanh_fast(acc[3]);
                uint_t p01 = ((uint_t)f2bf(t1) << 16) | f2bf(t0);
                uint_t p23 = ((uint_t)f2bf(t3) << 16) | f2bf(t2);
                uint_t* hp = &hbuf[wv][st][s16][t4 * 8 + quad * 2];
                hp[0] = p01;
                hp[1] = p23;
            }
        }
        // ---- GEMM2: block-diag W2 against the 64 fresh h k-rows (wave-private LDS) ----
        {
            const ushort_t* w2p = w2full + (mt * 16 + s16) * 64;
            short8 c0 = *(const short8*)(w2p + quad * 8);
            short8 c1 = *(const short8*)(w2p + 32 + quad * 8);
            const int l0 = mt * 8 + quad * 2;           // this lane's first l
            const float4 b2v = *(const float4*)(b2f + l0 * 2);
            const bool pad = (l0 == 62);                // l=63 slot is padding -> handles d=0
            #pragma unroll
            for (int st = 0; st < 2; ++st) {
                short8 h0 = *(const short8*)&hbuf[wv][st][s16][quad * 4];
                short8 h1 = *(const short8*)&hbuf[wv][st][s16][16 + quad * 4];
                f32x4 acc2 = {0.f, 0.f, 0.f, 0.f};
                acc2 = __builtin_amdgcn_mfma_f32_16x16x32_bf16(c0, h0, acc2, 0, 0, 0);
                acc2 = __builtin_amdgcn_mfma_f32_16x16x32_bf16(c1, h1, acc2, 0, 0, 0);
                const int s = sbase + st * 16 + s16;
                float* zr = out + (size_t)s * DIMS;
                const float* xr = x + (size_t)s * DIMS;
                float mu0 = acc2[0] + b2v.x, al0 = acc2[1] + b2v.y;
                float mu1 = acc2[2] + b2v.z, al1 = acc2[3] + b2v.w;
                // slot0: l = l0, d = l0+1 (l0 <= 62 always valid)
                zr[l0 + 1] = fmaf(xr[l0 + 1], __expf(al0), mu0);
                lsum[st] += al0;
                // slot1: l = l0+1 -> d = l0+2 ; pad lane handles d = 0 instead
                float alB = pad ? ip1 : al1;
                float muB = pad ? ip0 : mu1;
                int   d2  = pad ? 0   : (l0 + 2);
                zr[d2] = fmaf(xr[d2], __expf(alB), muB);
                lsum[st] += alB;
            }
        }
    }

    // log_det: sum lane partials across the 4 quads holding the same sample
    #pragma unroll
    for (int st = 0; st < 2; ++st) {
        float v = lsum[st];
        int r1 = __builtin_amdgcn_ds_swizzle(__float_as_int(v), 0x401F);  // xor 16
        v += __int_as_float(r1);
        int r2 = __builtin_amdgcn_ds_bpermute(((lane ^ 32) << 2), __float_as_int(v));
        v += __int_as_float(r2);
        if (quad == 0)
            out[(size_t)nB * DIMS + sbase + st * 16 + s16] = v;
    }
}

extern "C" void kernel_launch(void* const* d_in, const int* in_sizes, int n_in,
                              void* d_out, int out_size, void* d_ws, size_t ws_size,
                              hipStream_t stream) {
    const float* x  = (const float*)d_in[0];
    const float* ip = (const float*)d_in[1];
    const float* W1 = (const float*)d_in[2];
    const float* b1 = (const float*)d_in[3];
    const float* W2 = (const float*)d_in[4];
    const float* b2 = (const float*)d_in[5];
    ushort_t* ws = (ushort_t*)d_ws;
    float* out = (float*)d_out;

    const int nB = in_sizes[0] / DIMS;      // 131072
    const int prep_elems = 512 * 64 + 128 * 64 + 128;

    siaf_prep<<<(prep_elems + 255) / 256, 256, 0, stream>>>(W1, b1, W2, b2, ws);
    siaf_mfma<<<nB / 128, 256, 0, stream>>>(x, ip, ws, out, nB);
}

// Round 3
// 129.547 us; speedup vs baseline: 1.7617x; 1.2094x over previous
//
#include <hip/hip_runtime.h>

// SIAF forward via two fused transposed MFMA GEMMs (bf16 in, fp32 acc).
//   GEMM1: y[n=512][s] = sum_k w1b[n][k] * x[s][k]  (k=64; k==63 = bias col, x_k=1)
//   h = tanh(y) -> bf16 -> per-wave LDS rotating half-window (32 kl rows)
//   GEMM2: out2[r=128][s] accumulated in 2 half-k MFMAs; C-layout gives each lane
//          complete (mu,alpha) for 2 l-values -> in-lane epilogue.
// ALL global IO is coalesced 1KB/instruction; every scattered access lives in a
// bank-balanced XOR-swizzled LDS buffer:
//   xz[wave][32 samples][64]: x staged in, z written in-place, stored out at end.
// LDS/block = 32KB (xz) + 8KB (hb) = 40KB -> 4 blocks/CU (16 waves/CU).

#define DIMS 64

typedef __attribute__((ext_vector_type(8))) short short8;
typedef __attribute__((ext_vector_type(4))) float f32x4;
typedef unsigned short ushort_t;
typedef unsigned int uint_t;
typedef unsigned long long ull_t;

__device__ __forceinline__ ushort_t f2bf(float f) {
    uint_t u = __float_as_uint(f);
    u += 0x7FFFu + ((u >> 16) & 1u);   // RNE; data has no NaN/Inf
    return (ushort_t)(u >> 16);
}

// ws layout: w1b ushort[512][64] | w2full ushort[128][64] | b2f float[128]
__global__ void siaf_prep(const float* __restrict__ W1, const float* __restrict__ b1,
                          const float* __restrict__ W2, const float* __restrict__ b2,
                          ushort_t* __restrict__ ws_u) {
    ushort_t* w1b    = ws_u;
    ushort_t* w2full = ws_u + 512 * 64;
    float*    b2f    = (float*)(ws_u + 512 * 64 + 128 * 64);
    int i = blockIdx.x * 256 + threadIdx.x;
    if (i < 512 * 64) {
        int k = i & 63, n = i >> 6, l = n >> 3, h = n & 7;
        float v = 0.0f;
        if (l < 63) {
            if (k < 63 && k <= l) v = W1[(l * 8 + h) * 63 + k];
            else if (k == 63)     v = b1[l * 8 + h];
        }
        w1b[i] = f2bf(v);
    } else if (i < 512 * 64 + 128 * 64) {
        int j = i - 512 * 64;
        int kl = j & 63, r = j >> 6, l = r >> 1, o = r & 1;
        float v = 0.0f;
        if (l < 63 && (kl >> 3) == (l & 7)) v = W2[(l * 2 + o) * 8 + (kl & 7)];
        w2full[j] = f2bf(v);
    } else if (i < 512 * 64 + 128 * 64 + 128) {
        int j = i - (512 * 64 + 128 * 64);
        int l = j >> 1, o = j & 1;
        b2f[j] = (l < 63) ? b2[l * 2 + o] : 0.0f;
    }
}

__device__ __forceinline__ float tanh_fast(float y) {
    // tanh(y) = 1 - 2/(exp(2y)+1); v_rcp is plenty accurate vs bf16 rounding.
    float e = __expf(2.0f * y);
    float r = __builtin_amdgcn_rcpf(e + 1.0f);
    return fmaf(-2.0f, r, 1.0f);
}

__global__ __launch_bounds__(256, 4) void siaf_mfma(
        const float* __restrict__ x, const float* __restrict__ ip,
        const ushort_t* __restrict__ ws_u, float* __restrict__ out, int nB) {
    const ushort_t* w1b    = ws_u;
    const ushort_t* w2full = ws_u + 512 * 64;
    const float*    b2f    = (const float*)(ws_u + 512 * 64 + 128 * 64);

    __shared__ float  xz[4][32 * 64];     // [wave][s_loc][64], 16B-chunk XOR swizzle
    __shared__ uint_t hb[4][2][16 * 16];  // [wave][st][s16][16 dw], chunk XOR swizzle

    const int tid  = threadIdx.x;
    const int wv   = tid >> 6, lane = tid & 63;
    const int s16  = lane & 15, quad = lane >> 4;
    const int sbase = blockIdx.x * 128 + wv * 32;

    float* xzw = xz[wv];

    // ---- phase 1: coalesced global -> LDS (1KB per wave instruction) ----
    #pragma unroll
    for (int g = 0; g < 8; ++g) {
        const float4 v = ((const float4*)(x + (size_t)(sbase + 4 * g) * DIMS))[lane];
        const int s_loc = 4 * g + quad;
        const int chunk = (lane & 15) ^ (s_loc & 15);
        *(float4*)(xzw + s_loc * 64 + chunk * 4) = v;
    }

    const float ip0 = ip[0], ip1 = ip[1];

    // ---- phase 2: B-frags (x rows, bf16) from LDS; k=63 elem := 1.0 (bias) ----
    short8 bfr[2][2];
    float lsum[2] = {0.0f, 0.0f};
    #pragma unroll
    for (int st = 0; st < 2; ++st) {
        const int s_loc = st * 16 + s16;
        #pragma unroll
        for (int kh = 0; kh < 2; ++kh) {
            const int c0 = kh * 8 + quad * 2;
            float4 va = *(const float4*)(xzw + s_loc * 64 + ((c0 ^ s16) & 15) * 4);
            float4 vb = *(const float4*)(xzw + s_loc * 64 + (((c0 + 1) ^ s16) & 15) * 4);
            float f[8] = {va.x, va.y, va.z, va.w, vb.x, vb.y, vb.z, vb.w};
            if (kh == 1 && quad == 3) f[7] = 1.0f;   // bias column
            short8 t;
            #pragma unroll
            for (int j = 0; j < 8; ++j) t[j] = (short)f2bf(f[j]);
            bfr[st][kh] = t;
        }
    }

    for (int mt = 0; mt < 8; ++mt) {
        const ushort_t* w2p = w2full + (mt * 16 + s16) * 64 + quad * 8;
        f32x4 acc2[2] = {{0.f, 0.f, 0.f, 0.f}, {0.f, 0.f, 0.f, 0.f}};

        #pragma unroll
        for (int t4 = 0; t4 < 4; ++t4) {
            const ushort_t* w1p = w1b + ((mt * 4 + t4) * 16 + s16) * 64 + quad * 8;
            const short8 a0 = *(const short8*)(w1p);
            const short8 a1 = *(const short8*)(w1p + 32);
            #pragma unroll
            for (int st = 0; st < 2; ++st) {
                f32x4 acc = {0.f, 0.f, 0.f, 0.f};
                acc = __builtin_amdgcn_mfma_f32_16x16x32_bf16(a0, bfr[st][0], acc, 0, 0, 0);
                acc = __builtin_amdgcn_mfma_f32_16x16x32_bf16(a1, bfr[st][1], acc, 0, 0, 0);
                const float t0 = tanh_fast(acc[0]), t1 = tanh_fast(acc[1]);
                const float t2 = tanh_fast(acc[2]), t3 = tanh_fast(acc[3]);
                const uint_t p01 = ((uint_t)f2bf(t1) << 16) | f2bf(t0);
                const uint_t p23 = ((uint_t)f2bf(t3) << 16) | f2bf(t2);
                const int idx = (t4 & 1) * 8 + quad * 2;             // even
                const int ph  = (((idx >> 2) ^ (s16 & 3)) << 2) | (idx & 3);
                *(ull_t*)&hb[wv][st][s16 * 16 + ph] = ((ull_t)p23 << 32) | p01;
            }
            if (t4 & 1) {  // one k=32 half-window of GEMM2 ready
                const int half = t4 >> 1;
                const short8 ch = *(const short8*)(w2p + half * 32);
                #pragma unroll
                for (int st = 0; st < 2; ++st) {
                    const int ph = (quad ^ (s16 & 3)) << 2;
                    const short8 hfr = *(const short8*)&hb[wv][st][s16 * 16 + ph];
                    acc2[st] = __builtin_amdgcn_mfma_f32_16x16x32_bf16(ch, hfr, acc2[st], 0, 0, 0);
                }
            }
        }

        // ---- epilogue for l = mt*8 .. mt*8+7: z in-place in LDS ----
        const int l0 = mt * 8 + quad * 2;
        const float4 b2v = *(const float4*)(b2f + l0 * 2);
        const bool pad = (l0 == 62);            // l=63 slot is padding -> handles d=0
        #pragma unroll
        for (int st = 0; st < 2; ++st) {
            const int s_loc = st * 16 + s16;
            float mu0 = acc2[st][0] + b2v.x, al0 = acc2[st][1] + b2v.y;
            float mu1 = acc2[st][2] + b2v.z, al1 = acc2[st][3] + b2v.w;
            const int d1 = l0 + 1;
            float* p1 = xzw + s_loc * 64 + (((((d1 >> 2) ^ s16) & 15) << 2) | (d1 & 3));
            *p1 = fmaf(*p1, __expf(al0), mu0);
            lsum[st] += al0;
            const float alB = pad ? ip1 : al1;
            const float muB = pad ? ip0 : mu1;
            const int d2 = pad ? 0 : (l0 + 2);
            float* p2 = xzw + s_loc * 64 + (((((d2 >> 2) ^ s16) & 15) << 2) | (d2 & 3));
            *p2 = fmaf(*p2, __expf(alB), muB);
            lsum[st] += alB;
        }
    }

    // ---- phase 4: coalesced LDS -> global z store ----
    #pragma unroll
    for (int g = 0; g < 8; ++g) {
        const int s_loc = 4 * g + quad;
        const int chunk = (lane & 15) ^ (s_loc & 15);
        const float4 v = *(const float4*)(xzw + s_loc * 64 + chunk * 4);
        ((float4*)(out + (size_t)(sbase + 4 * g) * DIMS))[lane] = v;
    }

    // ---- log_det: sum the 4 quad-partials per sample ----
    #pragma unroll
    for (int st = 0; st < 2; ++st) {
        float v = lsum[st];
        int r1 = __builtin_amdgcn_ds_swizzle(__float_as_int(v), 0x401F);  // xor 16
        v += __int_as_float(r1);
        int r2 = __builtin_amdgcn_ds_bpermute((lane ^ 32) << 2, __float_as_int(v));
        v += __int_as_float(r2);
        if (quad == 0)
            out[(size_t)nB * DIMS + sbase + st * 16 + s16] = v;
    }
}

extern "C" void kernel_launch(void* const* d_in, const int* in_sizes, int n_in,
                              void* d_out, int out_size, void* d_ws, size_t ws_size,
                              hipStream_t stream) {
    const float* x  = (const float*)d_in[0];
    const float* ip = (const float*)d_in[1];
    const float* W1 = (const float*)d_in[2];
    const float* b1 = (const float*)d_in[3];
    const float* W2 = (const float*)d_in[4];
    const float* b2 = (const float*)d_in[5];
    ushort_t* ws = (ushort_t*)d_ws;
    float* out = (float*)d_out;

    const int nB = in_sizes[0] / DIMS;      // 131072
    const int prep_elems = 512 * 64 + 128 * 64 + 128;

    siaf_prep<<<(prep_elems + 255) / 256, 256, 0, stream>>>(W1, b1, W2, b2, ws);
    siaf_mfma<<<nB / 128, 256, 0, stream>>>(x, ip, ws, out, nB);
}